// Round 3
// baseline (249.716 us; speedup 1.0000x reference)
//
#include <hip/hip_runtime.h>
#include <stdint.h>

typedef __attribute__((ext_vector_type(4))) float f32x4;
typedef __attribute__((ext_vector_type(8))) short bf16x8;
typedef __attribute__((ext_vector_type(8))) unsigned short u16x8;
typedef __attribute__((ext_vector_type(4))) unsigned short u16x4;

#define NPIX 100352      // 32*56*56
#define CDIM 256
#define QKVN 768
#define HWDIM 56

__device__ __forceinline__ unsigned short f2bf(float f) {
  union { float f; unsigned int u; } cv; cv.f = f;
  unsigned int u = cv.u;
  unsigned int r = (u + 0x7FFFu + ((u >> 16) & 1u)) >> 16;
  return (unsigned short)r;
}

// ---------------- fp32 -> bf16 convert (8 elems/thread) ----------------
__global__ __launch_bounds__(256) void cvt_kernel(const float* __restrict__ in,
                                                  unsigned short* __restrict__ out,
                                                  int n8) {
  int i = blockIdx.x * 256 + threadIdx.x;
  if (i >= n8) return;
  const float4* p = reinterpret_cast<const float4*>(in) + (size_t)i * 2;
  float4 a = p[0], b = p[1];
  u16x8 r;
  r[0] = f2bf(a.x); r[1] = f2bf(a.y); r[2] = f2bf(a.z); r[3] = f2bf(a.w);
  r[4] = f2bf(b.x); r[5] = f2bf(b.y); r[6] = f2bf(b.z); r[7] = f2bf(b.w);
  *(reinterpret_cast<u16x8*>(out) + i) = r;
}

// ---------------- bf16 MFMA GEMM: C[M,N] = A[M,K] * Bt[N,K]^T + bias ----------------
__device__ __forceinline__ void gload16(const unsigned short* g, unsigned short* l) {
  __builtin_amdgcn_global_load_lds((const __attribute__((address_space(1))) void*)g,
                                   (__attribute__((address_space(3))) void*)l, 16, 0, 0);
}

template<bool OUT_BF16>
__global__ __launch_bounds__(256) void gemm_kernel(
    const unsigned short* __restrict__ A,
    const unsigned short* __restrict__ Bt,
    const float* __restrict__ bias,
    void* __restrict__ out,
    int M, int N, int K)
{
  __shared__ unsigned short As[2][128 * 32];
  __shared__ unsigned short Bs[2][128 * 32];
  const int t = threadIdx.x;
  const int lane = t & 63;
  const int wave = t >> 6;
  const int wr = wave >> 1, wc = wave & 1;
  const long m0 = (long)blockIdx.x * 128;
  const long n0 = (long)blockIdx.y * 128;
  const int nsteps = K >> 5;
  const int r0 = lane & 15;
  const int kh = lane >> 4;

  f32x4 acc[4][4] = {};

  const unsigned short* gA = A + m0 * K;
  const unsigned short* gB = Bt + n0 * K;

  {
    #pragma unroll
    for (int j = 0; j < 2; ++j) {
      int c = t + 256 * j;
      int row = c >> 2, ko = (c & 3) << 3;
      gload16(gA + (size_t)row * K + ko, &As[0][c * 8]);
      gload16(gB + (size_t)row * K + ko, &Bs[0][c * 8]);
    }
  }
  __syncthreads();

  for (int s = 0; s < nsteps; ++s) {
    int cur = s & 1;
    if (s + 1 < nsteps) {
      const unsigned short* gA2 = gA + (s + 1) * 32;
      const unsigned short* gB2 = gB + (s + 1) * 32;
      #pragma unroll
      for (int j = 0; j < 2; ++j) {
        int c = t + 256 * j;
        int row = c >> 2, ko = (c & 3) << 3;
        gload16(gA2 + (size_t)row * K + ko, &As[cur ^ 1][c * 8]);
        gload16(gB2 + (size_t)row * K + ko, &Bs[cur ^ 1][c * 8]);
      }
    }
    bf16x8 af[4], bfr[4];
    #pragma unroll
    for (int mf = 0; mf < 4; ++mf)
      af[mf] = *reinterpret_cast<const bf16x8*>(&As[cur][(wr * 64 + mf * 16 + r0) * 32 + kh * 8]);
    #pragma unroll
    for (int nf = 0; nf < 4; ++nf)
      bfr[nf] = *reinterpret_cast<const bf16x8*>(&Bs[cur][(wc * 64 + nf * 16 + r0) * 32 + kh * 8]);
    #pragma unroll
    for (int mf = 0; mf < 4; ++mf) {
      #pragma unroll
      for (int nf = 0; nf < 4; ++nf)
        acc[mf][nf] = __builtin_amdgcn_mfma_f32_16x16x32_bf16(af[mf], bfr[nf], acc[mf][nf], 0, 0, 0);
    }
    __syncthreads();
  }

  #pragma unroll
  for (int mf = 0; mf < 4; ++mf) {
    #pragma unroll
    for (int nf = 0; nf < 4; ++nf) {
      long col = n0 + wc * 64 + nf * 16 + r0;
      float bv = bias[col];
      #pragma unroll
      for (int r = 0; r < 4; ++r) {
        long row = m0 + wr * 64 + mf * 16 + kh * 4 + r;
        float v = acc[mf][nf][r] + bv;
        if (OUT_BF16) ((unsigned short*)out)[row * N + col] = f2bf(v);
        else          ((float*)out)[row * N + col] = v;
      }
    }
  }
}

// ---------------- shifted-window attention (S^T form, 8 waves = 8 heads) ----------------
// block = window (512 threads); wave w = head w
__global__ __launch_bounds__(512, 4) void attn_kernel(
    const unsigned short* __restrict__ qkv,   // [NPIX][768] bf16, pixel order
    const float* __restrict__ table,          // [169][8]
    unsigned short* __restrict__ aout)        // [NPIX][256] bf16, pixel order
{
  const int win = blockIdx.x;
  const int b = win >> 6;
  const int gi = (win >> 3) & 7;
  const int gj = win & 7;
  const int t = threadIdx.x;
  const int head = t >> 6;
  const int lane = t & 63;
  const int fr = lane & 15;     // fragment col lane part
  const int q = lane >> 4;      // lane quarter

  __shared__ unsigned short Vt[8][32 * 70];   // per head: Vt[d][j], stride 70
  __shared__ float tb_s[8][176];              // bias table, head-major
  __shared__ int pix_s[64];

  if (t < 64) {
    int idx = (t < 49) ? t : 48;
    int wi = idx / 7, wj = idx - (idx / 7) * 7;
    int hs = gi * 7 + wi, ws = gj * 7 + wj;
    int ph = hs + 3; if (ph >= HWDIM) ph -= HWDIM;
    int pw = ws + 3; if (pw >= HWDIM) pw -= HWDIM;
    pix_s[t] = (b * HWDIM + ph) * HWDIM + pw;
  }
  for (int l = t; l < 1352; l += 512)
    tb_s[l & 7][l >> 3] = table[l];
  __syncthreads();   // the only block-wide barrier

  unsigned short* VtW = Vt[head];

  // ---- V -> LDS transposed (stride 70: conflict-free scatter) ----
  {
    int c = (lane & 3) * 8;
    #pragma unroll
    for (int it = 0; it < 4; ++it) {
      int j = (lane >> 2) + it * 16;
      u16x8 vv = {0, 0, 0, 0, 0, 0, 0, 0};
      if (j < 49)
        vv = *reinterpret_cast<const u16x8*>(
            qkv + (size_t)pix_s[j] * QKVN + 512 + head * 32 + c);
      #pragma unroll
      for (int e = 0; e < 8; ++e) VtW[(c + e) * 70 + j] = vv[e];
    }
  }

  // ---- Q/K fragments direct from global ----
  bf16x8 kf[4], qf[4];
  #pragma unroll
  for (int f = 0; f < 4; ++f) {
    int rj = f * 16 + fr;
    int p = pix_s[(rj < 49) ? rj : 48];
    const unsigned short* base = qkv + (size_t)p * QKVN + head * 32 + q * 8;
    qf[f] = *reinterpret_cast<const bf16x8*>(base);
    kf[f] = *reinterpret_cast<const bf16x8*>(base + 256);
  }

  // ---- S^T = K·Q^T: acc rows j, cols i ----
  f32x4 acc[4][4] = {};   // [jf][if]
  #pragma unroll
  for (int jf = 0; jf < 4; ++jf) {
    #pragma unroll
    for (int c2 = 0; c2 < 4; ++c2)
      acc[jf][c2] = __builtin_amdgcn_mfma_f32_16x16x32_bf16(kf[jf], qf[c2], acc[jf][c2], 0, 0, 0);
  }

  // ---- softmax over rows j (no max-subtract; masked/pad -> exp -> 0) ----
  const float scale = 0.17677669529663687f;  // 1/sqrt(32)
  int iwi[4], iwj[4], ireg[4];
  #pragma unroll
  for (int c2 = 0; c2 < 4; ++c2) {
    int i = c2 * 16 + fr; if (i > 48) i = 48;
    iwi[c2] = i / 7; iwj[c2] = i - iwi[c2] * 7;
    int rh = (gi < 7) ? 0 : ((iwi[c2] < 4) ? 1 : 2);
    int rw = (gj < 7) ? 0 : ((iwj[c2] < 4) ? 1 : 2);
    ireg[c2] = rh * 3 + rw;
  }
  float colsum[4] = {0.f, 0.f, 0.f, 0.f};
  unsigned pk[4][4][2];     // [jf][if][word]: bf16 pairs (r0|r1, r2|r3)
  const float* tbh = tb_s[head];
  #pragma unroll
  for (int jf = 0; jf < 4; ++jf) {
    unsigned lo[4];
    #pragma unroll
    for (int r = 0; r < 4; ++r) {
      int j = jf * 16 + q * 4 + r;
      bool jok = j < 49;
      int jc = jok ? j : 48;
      int jwi = jc / 7, jwj = jc - (jc / 7) * 7;
      int jrh = (gi < 7) ? 0 : ((jwi < 4) ? 1 : 2);
      int jrw = (gj < 7) ? 0 : ((jwj < 4) ? 1 : 2);
      int jreg = jrh * 3 + jrw;
      #pragma unroll
      for (int c2 = 0; c2 < 4; ++c2) {
        int idx = (iwi[c2] - jwi + 6) * 13 + (iwj[c2] - jwj + 6);
        float add = tbh[idx] + ((ireg[c2] == jreg) ? 0.f : -100.f);
        float val = jok ? (acc[jf][c2][r] * scale + add) : -1e30f;
        float e = __expf(val);
        colsum[c2] += e;
        unsigned h = f2bf(e);
        if ((r & 1) == 0) lo[c2] = h;
        else pk[jf][c2][r >> 1] = lo[c2] | (h << 16);
      }
    }
  }
  float rinv[4];
  #pragma unroll
  for (int c2 = 0; c2 < 4; ++c2) {
    float s = colsum[c2];
    s += __shfl_xor(s, 16);
    s += __shfl_xor(s, 32);
    rinv[c2] = 1.0f / s;
  }

  // ---- PV: out^T[d][i] = sum_j Vt[d][j] * P^T[j][i], B-frag via lane remap ----
  const int srcA = ((q & 1) << 5) + fr;   // source quarter 2*(q&1)
  const int srcB = srcA + 16;
  const bool hi = (q >= 2);               // jf select within kb

  f32x4 outT[2][4] = {};   // [nt(d-block)][if]
  #pragma unroll
  for (int kb = 0; kb < 2; ++kb) {
    bf16x8 vfrag[2];
    #pragma unroll
    for (int nt = 0; nt < 2; ++nt)
      vfrag[nt] = *reinterpret_cast<const bf16x8*>(&VtW[(nt * 16 + fr) * 70 + kb * 32 + q * 8]);
    #pragma unroll
    for (int c2 = 0; c2 < 4; ++c2) {
      unsigned a0 = (unsigned)__shfl((int)pk[2 * kb][c2][0], srcA);
      unsigned a1 = (unsigned)__shfl((int)pk[2 * kb][c2][1], srcA);
      unsigned a2 = (unsigned)__shfl((int)pk[2 * kb][c2][0], srcB);
      unsigned a3 = (unsigned)__shfl((int)pk[2 * kb][c2][1], srcB);
      unsigned b0 = (unsigned)__shfl((int)pk[2 * kb + 1][c2][0], srcA);
      unsigned b1 = (unsigned)__shfl((int)pk[2 * kb + 1][c2][1], srcA);
      unsigned b2 = (unsigned)__shfl((int)pk[2 * kb + 1][c2][0], srcB);
      unsigned b3 = (unsigned)__shfl((int)pk[2 * kb + 1][c2][1], srcB);
      union { unsigned u[4]; bf16x8 v; } pf;
      pf.u[0] = hi ? b0 : a0;
      pf.u[1] = hi ? b1 : a1;
      pf.u[2] = hi ? b2 : a2;
      pf.u[3] = hi ? b3 : a3;
      #pragma unroll
      for (int nt = 0; nt < 2; ++nt)
        outT[nt][c2] = __builtin_amdgcn_mfma_f32_16x16x32_bf16(vfrag[nt], pf.v, outT[nt][c2], 0, 0, 0);
    }
  }

  // ---- store: lane owns pixel i = c2*16+fr, d-runs of 4 -> 8B stores ----
  #pragma unroll
  for (int c2 = 0; c2 < 4; ++c2) {
    int i = c2 * 16 + fr;
    if (i < 49) {
      float rv = rinv[c2];
      unsigned short* op = aout + (size_t)pix_s[i] * CDIM + head * 32 + q * 4;
      #pragma unroll
      for (int nt = 0; nt < 2; ++nt) {
        f32x4 o = outT[nt][c2];
        u16x4 pkd;
        pkd[0] = f2bf(o[0] * rv); pkd[1] = f2bf(o[1] * rv);
        pkd[2] = f2bf(o[2] * rv); pkd[3] = f2bf(o[3] * rv);
        *reinterpret_cast<u16x4*>(op + nt * 16) = pkd;
      }
    }
  }
}

// ---------------- launch ----------------
extern "C" void kernel_launch(void* const* d_in, const int* in_sizes, int n_in,
                              void* d_out, int out_size, void* d_ws, size_t ws_size,
                              hipStream_t stream) {
  const float* x      = (const float*)d_in[0];
  const float* qkv_w  = (const float*)d_in[1];
  const float* qkv_b  = (const float*)d_in[2];
  const float* proj_w = (const float*)d_in[3];
  const float* proj_b = (const float*)d_in[4];
  const float* table  = (const float*)d_in[5];

  char* ws = (char*)d_ws;
  unsigned short* x_bf    = (unsigned short*)ws;
  unsigned short* qkv_bf  = (unsigned short*)(ws + 51380224);
  unsigned short* qkvw_bf = (unsigned short*)(ws + 205520896);
  unsigned short* projw_bf= (unsigned short*)(ws + 205914112);
  unsigned short* aout    = x_bf;

  cvt_kernel<<<12544, 256, 0, stream>>>(x, x_bf, NPIX * CDIM / 8);
  cvt_kernel<<<96, 256, 0, stream>>>(qkv_w, qkvw_bf, QKVN * CDIM / 8);
  cvt_kernel<<<32, 256, 0, stream>>>(proj_w, projw_bf, CDIM * CDIM / 8);

  dim3 g1(NPIX / 128, QKVN / 128);
  gemm_kernel<true><<<g1, 256, 0, stream>>>(x_bf, qkvw_bf, qkv_b, qkv_bf,
                                            NPIX, QKVN, CDIM);

  attn_kernel<<<2048, 512, 0, stream>>>(qkv_bf, table, aout);

  dim3 g2(NPIX / 128, CDIM / 128);
  gemm_kernel<false><<<g2, 256, 0, stream>>>(aout, projw_bf, proj_b, (float*)d_out,
                                             NPIX, CDIM, CDIM);
}

// Round 4
// 205.827 us; speedup vs baseline: 1.2132x; 1.2132x over previous
//
#include <hip/hip_runtime.h>
#include <stdint.h>

typedef __attribute__((ext_vector_type(4))) float f32x4;
typedef __attribute__((ext_vector_type(8))) short bf16x8;
typedef __attribute__((ext_vector_type(8))) unsigned short u16x8;
typedef __attribute__((ext_vector_type(4))) unsigned short u16x4;

#define NPIX 100352      // 32*56*56
#define CDIM 256
#define QKVN 768
#define HWDIM 56

__device__ __forceinline__ unsigned short f2bf(float f) {
  union { float f; unsigned int u; } cv; cv.f = f;
  unsigned int u = cv.u;
  unsigned int r = (u + 0x7FFFu + ((u >> 16) & 1u)) >> 16;
  return (unsigned short)r;
}

// ---------------- fp32 -> bf16 convert (8 elems/thread) ----------------
__global__ __launch_bounds__(256) void cvt_kernel(const float* __restrict__ in,
                                                  unsigned short* __restrict__ out,
                                                  int n8) {
  int i = blockIdx.x * 256 + threadIdx.x;
  if (i >= n8) return;
  const float4* p = reinterpret_cast<const float4*>(in) + (size_t)i * 2;
  float4 a = p[0], b = p[1];
  u16x8 r;
  r[0] = f2bf(a.x); r[1] = f2bf(a.y); r[2] = f2bf(a.z); r[3] = f2bf(a.w);
  r[4] = f2bf(b.x); r[5] = f2bf(b.y); r[6] = f2bf(b.z); r[7] = f2bf(b.w);
  *(reinterpret_cast<u16x8*>(out) + i) = r;
}

// ---------------- bf16 MFMA GEMM: C[M,N] = A[M,K] * Bt[N,K]^T + bias ----------------
// 1-D grid, XCD-aware swizzle: all NBN n-blocks of one m-tile run on one XCD.
__device__ __forceinline__ void gload16(const unsigned short* g, unsigned short* l) {
  __builtin_amdgcn_global_load_lds((const __attribute__((address_space(1))) void*)g,
                                   (__attribute__((address_space(3))) void*)l, 16, 0, 0);
}

template<bool OUT_BF16>
__global__ __launch_bounds__(256) void gemm_kernel(
    const unsigned short* __restrict__ A,
    const unsigned short* __restrict__ Bt,
    const float* __restrict__ bias,
    void* __restrict__ out,
    int M, int N, int K, int nbn)
{
  __shared__ unsigned short As[2][128 * 32];
  __shared__ unsigned short Bs[2][128 * 32];
  const int t = threadIdx.x;
  const int lane = t & 63;
  const int wave = t >> 6;
  const int wr = wave >> 1, wc = wave & 1;

  // XCD swizzle: p%8 = XCD (round-robin dispatch); group NBN consecutive
  // slots (same m-tile, all n) on one XCD so the A-tile L2-hits.
  const int p = blockIdx.x;
  const int slot = p >> 3;
  const int g = slot / nbn;
  const int mi = (p & 7) + (g << 3);
  const int ni = slot - g * nbn;
  const long m0 = (long)mi * 128;
  const long n0 = (long)ni * 128;

  const int nsteps = K >> 5;
  const int r0 = lane & 15;
  const int kh = lane >> 4;

  f32x4 acc[4][4] = {};

  const unsigned short* gA = A + m0 * K;
  const unsigned short* gB = Bt + n0 * K;

  {
    #pragma unroll
    for (int j = 0; j < 2; ++j) {
      int c = t + 256 * j;
      int row = c >> 2, ko = (c & 3) << 3;
      gload16(gA + (size_t)row * K + ko, &As[0][c * 8]);
      gload16(gB + (size_t)row * K + ko, &Bs[0][c * 8]);
    }
  }
  __syncthreads();

  for (int s = 0; s < nsteps; ++s) {
    int cur = s & 1;
    if (s + 1 < nsteps) {
      const unsigned short* gA2 = gA + (s + 1) * 32;
      const unsigned short* gB2 = gB + (s + 1) * 32;
      #pragma unroll
      for (int j = 0; j < 2; ++j) {
        int c = t + 256 * j;
        int row = c >> 2, ko = (c & 3) << 3;
        gload16(gA2 + (size_t)row * K + ko, &As[cur ^ 1][c * 8]);
        gload16(gB2 + (size_t)row * K + ko, &Bs[cur ^ 1][c * 8]);
      }
    }
    bf16x8 af[4], bfr[4];
    #pragma unroll
    for (int mf = 0; mf < 4; ++mf)
      af[mf] = *reinterpret_cast<const bf16x8*>(&As[cur][(wr * 64 + mf * 16 + r0) * 32 + kh * 8]);
    #pragma unroll
    for (int nf = 0; nf < 4; ++nf)
      bfr[nf] = *reinterpret_cast<const bf16x8*>(&Bs[cur][(wc * 64 + nf * 16 + r0) * 32 + kh * 8]);
    #pragma unroll
    for (int mf = 0; mf < 4; ++mf) {
      #pragma unroll
      for (int nf = 0; nf < 4; ++nf)
        acc[mf][nf] = __builtin_amdgcn_mfma_f32_16x16x32_bf16(af[mf], bfr[nf], acc[mf][nf], 0, 0, 0);
    }
    __syncthreads();
  }

  #pragma unroll
  for (int mf = 0; mf < 4; ++mf) {
    #pragma unroll
    for (int nf = 0; nf < 4; ++nf) {
      long col = n0 + wc * 64 + nf * 16 + r0;
      float bv = bias[col];
      #pragma unroll
      for (int r = 0; r < 4; ++r) {
        long row = m0 + wr * 64 + mf * 16 + kh * 4 + r;
        float v = acc[mf][nf][r] + bv;
        if (OUT_BF16) ((unsigned short*)out)[row * N + col] = f2bf(v);
        else          ((float*)out)[row * N + col] = v;
      }
    }
  }
}

// ---------------- shifted-window attention (S^T form, 8 waves = 8 heads) ----------------
// block = window (512 threads); wave w = head w
__global__ __launch_bounds__(512, 4) void attn_kernel(
    const unsigned short* __restrict__ qkv,   // [NPIX][768] bf16, pixel order
    const float* __restrict__ table,          // [169][8]
    unsigned short* __restrict__ aout)        // [NPIX][256] bf16, pixel order
{
  const int win = blockIdx.x;
  const int b = win >> 6;
  const int gi = (win >> 3) & 7;
  const int gj = win & 7;
  const int t = threadIdx.x;
  const int head = t >> 6;
  const int lane = t & 63;
  const int fr = lane & 15;     // fragment col lane part
  const int q = lane >> 4;      // lane quarter

  __shared__ unsigned short Vt[8][32 * 70];   // per head: Vt[d][j], stride 70; reused as out_s
  __shared__ float tb_s[8][176];              // bias table, head-major
  __shared__ int pix_s[64];

  if (t < 64) {
    int idx = (t < 49) ? t : 48;
    int wi = idx / 7, wj = idx - (idx / 7) * 7;
    int hs = gi * 7 + wi, ws = gj * 7 + wj;
    int ph = hs + 3; if (ph >= HWDIM) ph -= HWDIM;
    int pw = ws + 3; if (pw >= HWDIM) pw -= HWDIM;
    pix_s[t] = (b * HWDIM + ph) * HWDIM + pw;
  }
  for (int l = t; l < 1352; l += 512)
    tb_s[l & 7][l >> 3] = table[l];
  __syncthreads();

  unsigned short* VtW = Vt[head];

  // ---- V -> LDS transposed (stride 70: conflict-free scatter) ----
  {
    int c = (lane & 3) * 8;
    #pragma unroll
    for (int it = 0; it < 4; ++it) {
      int j = (lane >> 2) + it * 16;
      u16x8 vv = {0, 0, 0, 0, 0, 0, 0, 0};
      if (j < 49)
        vv = *reinterpret_cast<const u16x8*>(
            qkv + (size_t)pix_s[j] * QKVN + 512 + head * 32 + c);
      #pragma unroll
      for (int e = 0; e < 8; ++e) VtW[(c + e) * 70 + j] = vv[e];
    }
  }

  // ---- Q/K fragments direct from global ----
  bf16x8 kf[4], qf[4];
  #pragma unroll
  for (int f = 0; f < 4; ++f) {
    int rj = f * 16 + fr;
    int p = pix_s[(rj < 49) ? rj : 48];
    const unsigned short* base = qkv + (size_t)p * QKVN + head * 32 + q * 8;
    qf[f] = *reinterpret_cast<const bf16x8*>(base);
    kf[f] = *reinterpret_cast<const bf16x8*>(base + 256);
  }

  // ---- S^T = K·Q^T: acc rows j, cols i ----
  f32x4 acc[4][4] = {};   // [jf][if]
  #pragma unroll
  for (int jf = 0; jf < 4; ++jf) {
    #pragma unroll
    for (int c2 = 0; c2 < 4; ++c2)
      acc[jf][c2] = __builtin_amdgcn_mfma_f32_16x16x32_bf16(kf[jf], qf[c2], acc[jf][c2], 0, 0, 0);
  }

  // ---- softmax over rows j (no max-subtract; masked/pad -> exp -> 0) ----
  const float scale = 0.17677669529663687f;  // 1/sqrt(32)
  int iwi[4], iwj[4], ireg[4];
  #pragma unroll
  for (int c2 = 0; c2 < 4; ++c2) {
    int i = c2 * 16 + fr; if (i > 48) i = 48;
    iwi[c2] = i / 7; iwj[c2] = i - iwi[c2] * 7;
    int rh = (gi < 7) ? 0 : ((iwi[c2] < 4) ? 1 : 2);
    int rw = (gj < 7) ? 0 : ((iwj[c2] < 4) ? 1 : 2);
    ireg[c2] = rh * 3 + rw;
  }
  float colsum[4] = {0.f, 0.f, 0.f, 0.f};
  unsigned pk[4][4][2];     // [jf][if][word]: bf16 pairs (r0|r1, r2|r3)
  const float* tbh = tb_s[head];
  #pragma unroll
  for (int jf = 0; jf < 4; ++jf) {
    unsigned lo[4];
    #pragma unroll
    for (int r = 0; r < 4; ++r) {
      int j = jf * 16 + q * 4 + r;
      bool jok = j < 49;
      int jc = jok ? j : 48;
      int jwi = jc / 7, jwj = jc - (jc / 7) * 7;
      int jrh = (gi < 7) ? 0 : ((jwi < 4) ? 1 : 2);
      int jrw = (gj < 7) ? 0 : ((jwj < 4) ? 1 : 2);
      int jreg = jrh * 3 + jrw;
      #pragma unroll
      for (int c2 = 0; c2 < 4; ++c2) {
        int idx = (iwi[c2] - jwi + 6) * 13 + (iwj[c2] - jwj + 6);
        float add = tbh[idx] + ((ireg[c2] == jreg) ? 0.f : -100.f);
        float val = jok ? (acc[jf][c2][r] * scale + add) : -1e30f;
        float e = __expf(val);
        colsum[c2] += e;
        unsigned h = f2bf(e);
        if ((r & 1) == 0) lo[c2] = h;
        else pk[jf][c2][r >> 1] = lo[c2] | (h << 16);
      }
    }
  }
  float rinv[4];
  #pragma unroll
  for (int c2 = 0; c2 < 4; ++c2) {
    float s = colsum[c2];
    s += __shfl_xor(s, 16);
    s += __shfl_xor(s, 32);
    rinv[c2] = 1.0f / s;
  }

  // ---- PV: out^T[d][i] = sum_j Vt[d][j] * P^T[j][i], B-frag via lane remap ----
  const int srcA = ((q & 1) << 5) + fr;   // source quarter 2*(q&1)
  const int srcB = srcA + 16;
  const bool hi = (q >= 2);               // jf select within kb

  f32x4 outT[2][4] = {};   // [nt(d-block)][if]
  #pragma unroll
  for (int kb = 0; kb < 2; ++kb) {
    bf16x8 vfrag[2];
    #pragma unroll
    for (int nt = 0; nt < 2; ++nt)
      vfrag[nt] = *reinterpret_cast<const bf16x8*>(&VtW[(nt * 16 + fr) * 70 + kb * 32 + q * 8]);
    #pragma unroll
    for (int c2 = 0; c2 < 4; ++c2) {
      unsigned a0 = (unsigned)__shfl((int)pk[2 * kb][c2][0], srcA);
      unsigned a1 = (unsigned)__shfl((int)pk[2 * kb][c2][1], srcA);
      unsigned a2 = (unsigned)__shfl((int)pk[2 * kb][c2][0], srcB);
      unsigned a3 = (unsigned)__shfl((int)pk[2 * kb][c2][1], srcB);
      unsigned b0 = (unsigned)__shfl((int)pk[2 * kb + 1][c2][0], srcA);
      unsigned b1 = (unsigned)__shfl((int)pk[2 * kb + 1][c2][1], srcA);
      unsigned b2 = (unsigned)__shfl((int)pk[2 * kb + 1][c2][0], srcB);
      unsigned b3 = (unsigned)__shfl((int)pk[2 * kb + 1][c2][1], srcB);
      union { unsigned u[4]; bf16x8 v; } pf;
      pf.u[0] = hi ? b0 : a0;
      pf.u[1] = hi ? b1 : a1;
      pf.u[2] = hi ? b2 : a2;
      pf.u[3] = hi ? b3 : a3;
      #pragma unroll
      for (int nt = 0; nt < 2; ++nt)
        outT[nt][c2] = __builtin_amdgcn_mfma_f32_16x16x32_bf16(vfrag[nt], pf.v, outT[nt][c2], 0, 0, 0);
    }
  }

  // ---- stage output in LDS (reuse Vt region), then coalesced global write ----
  // plain layout out_s[i][256] bf16 (512 B/row); byte offsets XOR-swizzled
  // with (i&7)<<4 -> 2-way banks on store, full-line coalesced copy out.
  unsigned short* out_s = Vt[0];
  __syncthreads();   // all waves done reading Vt
  #pragma unroll
  for (int c2 = 0; c2 < 4; ++c2) {
    int i = c2 * 16 + fr;
    if (i < 49) {
      float rv = rinv[c2];
      unsigned m = (unsigned)((i & 7) << 4);
      #pragma unroll
      for (int nt = 0; nt < 2; ++nt) {
        f32x4 o = outT[nt][c2];
        u16x4 pkd;
        pkd[0] = f2bf(o[0] * rv); pkd[1] = f2bf(o[1] * rv);
        pkd[2] = f2bf(o[2] * rv); pkd[3] = f2bf(o[3] * rv);
        unsigned off = (unsigned)(i * 512 + head * 64 + nt * 32 + q * 8) ^ m;
        *reinterpret_cast<u16x4*>((char*)out_s + off) = pkd;
      }
    }
  }
  __syncthreads();
  for (int u = t; u < 1568; u += 512) {
    int row = u >> 5, seg = u & 31;
    unsigned off = (unsigned)(row * 512 + ((seg * 16) ^ ((row & 7) << 4)));
    u16x8 ch = *reinterpret_cast<const u16x8*>((const char*)out_s + off);
    *reinterpret_cast<u16x8*>((char*)(aout + (size_t)pix_s[row] * CDIM) + seg * 16) = ch;
  }
}

// ---------------- launch ----------------
extern "C" void kernel_launch(void* const* d_in, const int* in_sizes, int n_in,
                              void* d_out, int out_size, void* d_ws, size_t ws_size,
                              hipStream_t stream) {
  const float* x      = (const float*)d_in[0];
  const float* qkv_w  = (const float*)d_in[1];
  const float* qkv_b  = (const float*)d_in[2];
  const float* proj_w = (const float*)d_in[3];
  const float* proj_b = (const float*)d_in[4];
  const float* table  = (const float*)d_in[5];

  char* ws = (char*)d_ws;
  unsigned short* x_bf    = (unsigned short*)ws;
  unsigned short* qkv_bf  = (unsigned short*)(ws + 51380224);
  unsigned short* qkvw_bf = (unsigned short*)(ws + 205520896);
  unsigned short* projw_bf= (unsigned short*)(ws + 205914112);
  unsigned short* aout    = x_bf;

  cvt_kernel<<<12544, 256, 0, stream>>>(x, x_bf, NPIX * CDIM / 8);
  cvt_kernel<<<96, 256, 0, stream>>>(qkv_w, qkvw_bf, QKVN * CDIM / 8);
  cvt_kernel<<<32, 256, 0, stream>>>(proj_w, projw_bf, CDIM * CDIM / 8);

  // QKV GEMM: 784 m-tiles x 6 n-tiles, XCD-swizzled 1-D grid
  gemm_kernel<true><<<784 * 6, 256, 0, stream>>>(x_bf, qkvw_bf, qkv_b, qkv_bf,
                                                 NPIX, QKVN, CDIM, 6);

  attn_kernel<<<2048, 512, 0, stream>>>(qkv_bf, table, aout);

  // proj GEMM: 784 m-tiles x 2 n-tiles
  gemm_kernel<false><<<784 * 2, 256, 0, stream>>>(aout, projw_bf, proj_b, (float*)d_out,
                                                  NPIX, CDIM, CDIM, 2);
}

// Round 6
// 190.207 us; speedup vs baseline: 1.3129x; 1.0821x over previous
//
#include <hip/hip_runtime.h>
#include <stdint.h>

typedef __attribute__((ext_vector_type(4))) float f32x4;
typedef __attribute__((ext_vector_type(8))) short bf16x8;
typedef __attribute__((ext_vector_type(8))) unsigned short u16x8;
typedef __attribute__((ext_vector_type(4))) unsigned short u16x4;

#define NPIX 100352      // 32*56*56
#define CDIM 256
#define QKVN 768
#define HWDIM 56

__device__ __forceinline__ unsigned short f2bf(float f) {
  union { float f; unsigned int u; } cv; cv.f = f;
  unsigned int u = cv.u;
  unsigned int r = (u + 0x7FFFu + ((u >> 16) & 1u)) >> 16;
  return (unsigned short)r;
}
__device__ __forceinline__ float bf2f(unsigned short h) {
  union { unsigned int u; float f; } cv; cv.u = ((unsigned int)h) << 16;
  return cv.f;
}

// ---------------- fp32 -> bf16 convert (8 elems/thread) ----------------
__global__ __launch_bounds__(256) void cvt_kernel(const float* __restrict__ in,
                                                  unsigned short* __restrict__ out,
                                                  int n8) {
  int i = blockIdx.x * 256 + threadIdx.x;
  if (i >= n8) return;
  const float4* p = reinterpret_cast<const float4*>(in) + (size_t)i * 2;
  float4 a = p[0], b = p[1];
  u16x8 r;
  r[0] = f2bf(a.x); r[1] = f2bf(a.y); r[2] = f2bf(a.z); r[3] = f2bf(a.w);
  r[4] = f2bf(b.x); r[5] = f2bf(b.y); r[6] = f2bf(b.z); r[7] = f2bf(b.w);
  *(reinterpret_cast<u16x8*>(out) + i) = r;
}

// ---------------- bias+mask table precompute ----------------
// layout: [cls][head][jf][c2][q][fr][r] bf16 -> lane (q,fr) loads u16x4 per (jf,c2)
__global__ __launch_bounds__(256) void bias_pre(const float* __restrict__ table,
                                                unsigned short* __restrict__ bt) {
  int e = blockIdx.x * 256 + threadIdx.x;       // 131072 total
  int r  = e & 3;
  int fr = (e >> 2) & 15;
  int q  = (e >> 6) & 3;
  int c2 = (e >> 8) & 3;
  int jf = (e >> 10) & 3;
  int h  = (e >> 12) & 7;
  int cls = (e >> 15) & 3;
  int j = jf * 16 + q * 4 + r;
  int i = c2 * 16 + fr;
  float v;
  if (j > 48 || i > 48) {
    v = -1e30f;
  } else {
    int bh = cls >> 1, bw = cls & 1;
    int iwi = i / 7, iwj = i % 7;
    int jwi = j / 7, jwj = j % 7;
    int ireg = (bh ? ((iwi < 4) ? 1 : 2) : 0) * 3 + (bw ? ((iwj < 4) ? 1 : 2) : 0);
    int jreg = (bh ? ((jwi < 4) ? 1 : 2) : 0) * 3 + (bw ? ((jwj < 4) ? 1 : 2) : 0);
    float m = (ireg == jreg) ? 0.f : -100.f;
    v = table[((iwi - jwi + 6) * 13 + (iwj - jwj + 6)) * 8 + h] + m;
  }
  bt[e] = f2bf(v);
}

// ---------------- bf16 MFMA GEMM: C[M,N] = A[M,K] * Bt[N,K]^T + bias ----------------
__device__ __forceinline__ void gload16(const unsigned short* g, unsigned short* l) {
  __builtin_amdgcn_global_load_lds((const __attribute__((address_space(1))) void*)g,
                                   (__attribute__((address_space(3))) void*)l, 16, 0, 0);
}

template<bool OUT_BF16>
__global__ __launch_bounds__(256) void gemm_kernel(
    const unsigned short* __restrict__ A,
    const unsigned short* __restrict__ Bt,
    const float* __restrict__ bias,
    void* __restrict__ out,
    int M, int N, int K, int nbn)
{
  __shared__ unsigned short As[2][128 * 32];
  __shared__ unsigned short Bs[2][128 * 32];
  const int t = threadIdx.x;
  const int lane = t & 63;
  const int wave = t >> 6;
  const int wr = wave >> 1, wc = wave & 1;

  const int p = blockIdx.x;
  const int slot = p >> 3;
  const int g = slot / nbn;
  const int mi = (p & 7) + (g << 3);
  const int ni = slot - g * nbn;
  const long m0 = (long)mi * 128;
  const long n0 = (long)ni * 128;

  const int nsteps = K >> 5;
  const int r0 = lane & 15;
  const int kh = lane >> 4;

  f32x4 acc[4][4] = {};

  const unsigned short* gA = A + m0 * K;
  const unsigned short* gB = Bt + n0 * K;

  {
    #pragma unroll
    for (int j = 0; j < 2; ++j) {
      int c = t + 256 * j;
      int row = c >> 2, ko = (c & 3) << 3;
      gload16(gA + (size_t)row * K + ko, &As[0][c * 8]);
      gload16(gB + (size_t)row * K + ko, &Bs[0][c * 8]);
    }
  }
  __syncthreads();

  for (int s = 0; s < nsteps; ++s) {
    int cur = s & 1;
    if (s + 1 < nsteps) {
      const unsigned short* gA2 = gA + (s + 1) * 32;
      const unsigned short* gB2 = gB + (s + 1) * 32;
      #pragma unroll
      for (int j = 0; j < 2; ++j) {
        int c = t + 256 * j;
        int row = c >> 2, ko = (c & 3) << 3;
        gload16(gA2 + (size_t)row * K + ko, &As[cur ^ 1][c * 8]);
        gload16(gB2 + (size_t)row * K + ko, &Bs[cur ^ 1][c * 8]);
      }
    }
    bf16x8 af[4], bfr[4];
    #pragma unroll
    for (int mf = 0; mf < 4; ++mf)
      af[mf] = *reinterpret_cast<const bf16x8*>(&As[cur][(wr * 64 + mf * 16 + r0) * 32 + kh * 8]);
    #pragma unroll
    for (int nf = 0; nf < 4; ++nf)
      bfr[nf] = *reinterpret_cast<const bf16x8*>(&Bs[cur][(wc * 64 + nf * 16 + r0) * 32 + kh * 8]);
    #pragma unroll
    for (int mf = 0; mf < 4; ++mf) {
      #pragma unroll
      for (int nf = 0; nf < 4; ++nf)
        acc[mf][nf] = __builtin_amdgcn_mfma_f32_16x16x32_bf16(af[mf], bfr[nf], acc[mf][nf], 0, 0, 0);
    }
    __syncthreads();
  }

  #pragma unroll
  for (int mf = 0; mf < 4; ++mf) {
    #pragma unroll
    for (int nf = 0; nf < 4; ++nf) {
      long col = n0 + wc * 64 + nf * 16 + r0;
      float bv = bias[col];
      #pragma unroll
      for (int r = 0; r < 4; ++r) {
        long row = m0 + wr * 64 + mf * 16 + kh * 4 + r;
        float v = acc[mf][nf][r] + bv;
        if (OUT_BF16) ((unsigned short*)out)[row * N + col] = f2bf(v);
        else          ((float*)out)[row * N + col] = v;
      }
    }
  }
}

// ---------------- shifted-window attention (S^T form, 8 waves = 8 heads) ----------------
__global__ __launch_bounds__(512, 4) void attn_kernel(
    const unsigned short* __restrict__ qkv,   // [NPIX][768] bf16
    const unsigned short* __restrict__ btab,  // [4][8][4096] bf16 bias+mask, D-frag order
    unsigned short* __restrict__ aout)        // [NPIX][256] bf16
{
  const int win = blockIdx.x;
  const int b = win >> 6;
  const int gi = (win >> 3) & 7;
  const int gj = win & 7;
  const int t = threadIdx.x;
  const int head = t >> 6;
  const int lane = t & 63;
  const int fr = lane & 15;     // fragment col lane part
  const int q = lane >> 4;      // lane quarter

  __shared__ unsigned short Vt[8][32 * 70];   // per head: Vt[d][j], stride 70; reused as out_s
  __shared__ int pix_s[64];

  if (t < 64) {
    int idx = (t < 49) ? t : 48;
    int wi = idx / 7, wj = idx - (idx / 7) * 7;
    int hs = gi * 7 + wi, ws = gj * 7 + wj;
    int ph = hs + 3; if (ph >= HWDIM) ph -= HWDIM;
    int pw = ws + 3; if (pw >= HWDIM) pw -= HWDIM;
    pix_s[t] = (b * HWDIM + ph) * HWDIM + pw;
  }
  __syncthreads();

  unsigned short* VtW = Vt[head];
  const int cls = (((gi == 7) ? 1 : 0) << 1) | ((gj == 7) ? 1 : 0);
  const unsigned short* bth = btab + (((cls << 3) | head) << 12);

  // ---- V -> LDS transposed (stride 70: conflict-free scatter) ----
  {
    int c = (lane & 3) * 8;
    #pragma unroll
    for (int it = 0; it < 4; ++it) {
      int j = (lane >> 2) + it * 16;
      u16x8 vv = {0, 0, 0, 0, 0, 0, 0, 0};
      if (j < 49)
        vv = *reinterpret_cast<const u16x8*>(
            qkv + (size_t)pix_s[j] * QKVN + 512 + head * 32 + c);
      #pragma unroll
      for (int e = 0; e < 8; ++e) VtW[(c + e) * 70 + j] = vv[e];
    }
  }

  // ---- Q/K fragments direct from global ----
  bf16x8 kf[4], qf[4];
  #pragma unroll
  for (int f = 0; f < 4; ++f) {
    int rj = f * 16 + fr;
    int p = pix_s[(rj < 49) ? rj : 48];
    const unsigned short* base = qkv + (size_t)p * QKVN + head * 32 + q * 8;
    qf[f] = *reinterpret_cast<const bf16x8*>(base);
    kf[f] = *reinterpret_cast<const bf16x8*>(base + 256);
  }

  // prefetch bias frags for jf=0 (hide L2 latency under MFMAs)
  u16x4 aw[2][4];
  #pragma unroll
  for (int c2 = 0; c2 < 4; ++c2)
    aw[0][c2] = *reinterpret_cast<const u16x4*>(bth + (c2 << 8) + (q << 6) + (fr << 2));

  // ---- S^T = K·Q^T ----
  f32x4 acc[4][4] = {};   // [jf][if]
  #pragma unroll
  for (int jf = 0; jf < 4; ++jf) {
    #pragma unroll
    for (int c2 = 0; c2 < 4; ++c2)
      acc[jf][c2] = __builtin_amdgcn_mfma_f32_16x16x32_bf16(kf[jf], qf[c2], acc[jf][c2], 0, 0, 0);
  }

  // ---- softmax over rows j: val = acc*scale + (bias+mask); exp; colsum ----
  const float scale = 0.17677669529663687f;  // 1/sqrt(32)
  float colsum[4] = {0.f, 0.f, 0.f, 0.f};
  unsigned pk[4][4][2];     // [jf][if][word]: bf16 pairs (r0|r1, r2|r3)
  #pragma unroll
  for (int jf = 0; jf < 4; ++jf) {
    if (jf < 3) {
      #pragma unroll
      for (int c2 = 0; c2 < 4; ++c2)
        aw[(jf + 1) & 1][c2] = *reinterpret_cast<const u16x4*>(
            bth + (((jf + 1) * 4 + c2) << 8) + (q << 6) + (fr << 2));
    }
    #pragma unroll
    for (int c2 = 0; c2 < 4; ++c2) {
      float ev[4];
      #pragma unroll
      for (int r = 0; r < 4; ++r) {
        float val = fmaf(acc[jf][c2][r], scale, bf2f(aw[jf & 1][c2][r]));
        ev[r] = __expf(val);
        colsum[c2] += ev[r];
      }
      unsigned h0 = f2bf(ev[0]), h1 = f2bf(ev[1]);
      unsigned h2 = f2bf(ev[2]), h3 = f2bf(ev[3]);
      pk[jf][c2][0] = h0 | (h1 << 16);
      pk[jf][c2][1] = h2 | (h3 << 16);
    }
  }
  float rinv[4];
  #pragma unroll
  for (int c2 = 0; c2 < 4; ++c2) {
    float s = colsum[c2];
    s += __shfl_xor(s, 16);
    s += __shfl_xor(s, 32);
    rinv[c2] = 1.0f / s;
  }

  // ---- PV: out^T[d][i] = sum_j Vt[d][j] * P^T[j][i], B-frag via lane remap ----
  const int srcA = ((q & 1) << 5) + fr;
  const int srcB = srcA + 16;
  const bool hi = (q >= 2);

  f32x4 outT[2][4] = {};   // [nt(d-block)][if]
  #pragma unroll
  for (int kb = 0; kb < 2; ++kb) {
    bf16x8 vfrag[2];
    #pragma unroll
    for (int nt = 0; nt < 2; ++nt)
      vfrag[nt] = *reinterpret_cast<const bf16x8*>(&VtW[(nt * 16 + fr) * 70 + kb * 32 + q * 8]);
    #pragma unroll
    for (int c2 = 0; c2 < 4; ++c2) {
      unsigned a0 = (unsigned)__shfl((int)pk[2 * kb][c2][0], srcA);
      unsigned a1 = (unsigned)__shfl((int)pk[2 * kb][c2][1], srcA);
      unsigned a2 = (unsigned)__shfl((int)pk[2 * kb][c2][0], srcB);
      unsigned a3 = (unsigned)__shfl((int)pk[2 * kb][c2][1], srcB);
      unsigned b0 = (unsigned)__shfl((int)pk[2 * kb + 1][c2][0], srcA);
      unsigned b1 = (unsigned)__shfl((int)pk[2 * kb + 1][c2][1], srcA);
      unsigned b2 = (unsigned)__shfl((int)pk[2 * kb + 1][c2][0], srcB);
      unsigned b3 = (unsigned)__shfl((int)pk[2 * kb + 1][c2][1], srcB);
      union { unsigned u[4]; bf16x8 v; } pf;
      pf.u[0] = hi ? b0 : a0;
      pf.u[1] = hi ? b1 : a1;
      pf.u[2] = hi ? b2 : a2;
      pf.u[3] = hi ? b3 : a3;
      #pragma unroll
      for (int nt = 0; nt < 2; ++nt)
        outT[nt][c2] = __builtin_amdgcn_mfma_f32_16x16x32_bf16(vfrag[nt], pf.v, outT[nt][c2], 0, 0, 0);
    }
  }

  // ---- stage output in LDS (reuse Vt), then coalesced global write ----
  unsigned short* out_s = Vt[0];
  __syncthreads();
  #pragma unroll
  for (int c2 = 0; c2 < 4; ++c2) {
    int i = c2 * 16 + fr;
    if (i < 49) {
      float rv = rinv[c2];
      unsigned m = (unsigned)((i & 7) << 4);
      #pragma unroll
      for (int nt = 0; nt < 2; ++nt) {
        f32x4 o = outT[nt][c2];
        u16x4 pkd;
        pkd[0] = f2bf(o[0] * rv); pkd[1] = f2bf(o[1] * rv);
        pkd[2] = f2bf(o[2] * rv); pkd[3] = f2bf(o[3] * rv);
        unsigned off = (unsigned)(i * 512 + head * 64 + nt * 32 + q * 8) ^ m;
        *reinterpret_cast<u16x4*>((char*)out_s + off) = pkd;
      }
    }
  }
  __syncthreads();
  for (int u = t; u < 1568; u += 512) {
    int row = u >> 5, seg = u & 31;
    unsigned off = (unsigned)(row * 512 + ((seg * 16) ^ ((row & 7) << 4)));
    u16x8 ch = *reinterpret_cast<const u16x8*>((const char*)out_s + off);
    *reinterpret_cast<u16x8*>((char*)(aout + (size_t)pix_s[row] * CDIM) + seg * 16) = ch;
  }
}

// ---------------- launch ----------------
extern "C" void kernel_launch(void* const* d_in, const int* in_sizes, int n_in,
                              void* d_out, int out_size, void* d_ws, size_t ws_size,
                              hipStream_t stream) {
  const float* x      = (const float*)d_in[0];
  const float* qkv_w  = (const float*)d_in[1];
  const float* qkv_b  = (const float*)d_in[2];
  const float* proj_w = (const float*)d_in[3];
  const float* proj_b = (const float*)d_in[4];
  const float* table  = (const float*)d_in[5];

  char* ws = (char*)d_ws;
  unsigned short* x_bf    = (unsigned short*)ws;
  unsigned short* qkv_bf  = (unsigned short*)(ws + 51380224);
  unsigned short* qkvw_bf = (unsigned short*)(ws + 205520896);
  unsigned short* projw_bf= (unsigned short*)(ws + 205914112);
  unsigned short* btab    = (unsigned short*)(ws + 206045184);  // 256 KB
  unsigned short* aout    = x_bf;

  cvt_kernel<<<12544, 256, 0, stream>>>(x, x_bf, NPIX * CDIM / 8);
  cvt_kernel<<<96, 256, 0, stream>>>(qkv_w, qkvw_bf, QKVN * CDIM / 8);
  cvt_kernel<<<32, 256, 0, stream>>>(proj_w, projw_bf, CDIM * CDIM / 8);
  bias_pre<<<512, 256, 0, stream>>>(table, btab);

  gemm_kernel<true><<<784 * 6, 256, 0, stream>>>(x_bf, qkvw_bf, qkv_b, qkv_bf,
                                                 NPIX, QKVN, CDIM, 6);

  attn_kernel<<<2048, 512, 0, stream>>>(qkv_bf, btab, aout);

  gemm_kernel<false><<<784 * 2, 256, 0, stream>>>(aout, projw_bf, proj_b, (float*)d_out,
                                                  NPIX, CDIM, CDIM, 2);
}